// Round 1
// baseline (631.547 us; speedup 1.0000x reference)
//
#include <hip/hip_runtime.h>
#include <hip/hip_bf16.h>

// ---- problem constants (fixed by setup_inputs) ----
#define B_    4
#define LIN   13294
#define M_    (B_*LIN)     // 53176
#define D_    256
#define NH_   8
#define NL_   4
#define NP_   4
#define DFF_  1024

typedef __bf16 bf16;
typedef unsigned int uint;
typedef __attribute__((ext_vector_type(8))) __bf16 bfrag8;
typedef __attribute__((ext_vector_type(4))) __bf16 bf16x4;
typedef __attribute__((ext_vector_type(4))) float facc4;
typedef __attribute__((ext_vector_type(2))) float f32x2;

// ---------------- elementwise: q = src + pos (fp32 + bf16) ----------------
__global__ __launch_bounds__(256) void make_q(const float* __restrict__ src,
                                              const float* __restrict__ pos,
                                              float* __restrict__ q,
                                              bf16* __restrict__ qb, int n4) {
  int i = blockIdx.x * 256 + threadIdx.x;
  if (i >= n4) return;
  float4 s = ((const float4*)src)[i];
  float4 p = ((const float4*)pos)[i];
  float4 v = {s.x + p.x, s.y + p.y, s.z + p.z, s.w + p.w};
  ((float4*)q)[i] = v;
  bf16 t4[4] = {(bf16)v.x, (bf16)v.y, (bf16)v.z, (bf16)v.w};
  ((uint2*)qb)[i] = *(uint2*)t4;
}

// ---------------- weight prep: transpose + bf16 convert ----------------
// vowt packs value_w^T (rows 0..255), offs_w^T (256..511), attn_w^T (512..639).
__global__ __launch_bounds__(256) void prep_weights(
    const float* __restrict__ vw, const float* __restrict__ ow,
    const float* __restrict__ aw, const float* __restrict__ outw,
    const float* __restrict__ f1w, const float* __restrict__ f2w,
    const float* __restrict__ vb, const float* __restrict__ ob,
    const float* __restrict__ ab,
    bf16* __restrict__ vowt, bf16* __restrict__ outwt,
    bf16* __restrict__ f1wt, bf16* __restrict__ f2wt, float* __restrict__ vobias) {
  int seg = blockIdx.y;
  int idx = blockIdx.x * 256 + threadIdx.x;
  if (seg == 6) {
    if (idx < 256) vobias[idx] = vb[idx];
    else if (idx < 512) vobias[idx] = ob[idx - 256];
    else if (idx < 640) vobias[idx] = ab[idx - 512];
    return;
  }
  const float* W; bf16* Wt; int K, N;
  switch (seg) {
    case 0: W = vw;   Wt = vowt;              K = 256;  N = 256;  break;
    case 1: W = ow;   Wt = vowt + 256 * 256;  K = 256;  N = 256;  break;
    case 2: W = aw;   Wt = vowt + 512 * 256;  K = 256;  N = 128;  break;
    case 3: W = outw; Wt = outwt;             K = 256;  N = 256;  break;
    case 4: W = f1w;  Wt = f1wt;              K = 256;  N = 1024; break;
    default: W = f2w; Wt = f2wt;              K = 1024; N = 256;  break;
  }
  if (idx < K * N) {
    int n = idx / K, k = idx - n * K;
    Wt[idx] = (bf16)W[k * N + n];
  }
}

// ---------------- async 16B global -> LDS (offset 0 only: HW-verified form) ----
__device__ __forceinline__ void gload16(const bf16* g, bf16* l) {
  __builtin_amdgcn_global_load_lds(
      (const __attribute__((address_space(1))) uint*)g,
      (__attribute__((address_space(3))) uint*)l, 16, 0, 0);
}

// ---------------- 128x128 MFMA GEMM: C[M,N] = A[M,K] @ Bt[N,K]^T + bias ----------
// 4 waves, each a 64x64 quadrant (4x4 of 16x16x32 MFMAs).
// Staging: global_load_lds width=16, XOR chunk swizzle (conflict-free b128 reads),
// runtime k0 pointer-advance (immediate-offset form failed correctness in r3).
// MFMA operand-swapped (weights = Arg0) so each thread holds 4 consecutive N
// per acc quad -> packed 8B stores.
template<int K, bool RELU>
__global__ __launch_bounds__(256) void gemm128(
    const bf16* __restrict__ A, const bf16* __restrict__ Bt,
    const float* __restrict__ bias, bf16* __restrict__ C,
    int Mdim, int N) {
  __shared__ __align__(16) bf16 As[128 * 64];
  __shared__ __align__(16) bf16 Bs[128 * 64];
  const int t = threadIdx.x, wave = t >> 6, lane = t & 63;
  const int m0 = blockIdx.x * 128, n0 = blockIdx.y * 128;
  const int wr = wave >> 1, wc = wave & 1;
  const int ln = lane & 15, quad = lane >> 4;
  const int sr = lane >> 3, cc = lane & 7;
  const int gcol = (cc ^ sr) * 8;            // swizzled 16B chunk within the 64-col row

  const bf16* ap[4]; const bf16* bp[4];
  bf16* la[4]; bf16* lb[4];
  #pragma unroll
  for (int ii = 0; ii < 4; ii++) {
    int i = wave * 4 + ii;                   // 8-row chunk id 0..15
    int arow = min(m0 + i * 8 + sr, Mdim - 1);
    ap[ii] = A + (size_t)arow * K + gcol;
    bp[ii] = Bt + (size_t)(n0 + i * 8 + sr) * K + gcol;
    la[ii] = As + i * 512;
    lb[ii] = Bs + i * 512;
  }
  // LDS byte offsets (ks=0); ks=1 is off ^ 64 (slot xor 4)
  int a_off[4], b_off[4];
  #pragma unroll
  for (int i = 0; i < 4; i++) {
    int ra = wr * 64 + i * 16 + ln;
    int rb = wc * 64 + i * 16 + ln;
    a_off[i] = ra * 128 + ((quad ^ (ra & 7)) * 16);
    b_off[i] = rb * 128 + ((quad ^ (rb & 7)) * 16);
  }

  facc4 acc[4][4];
  #pragma unroll
  for (int mt = 0; mt < 4; mt++)
    #pragma unroll
    for (int nt = 0; nt < 4; nt++) acc[mt][nt] = (facc4){0.f, 0.f, 0.f, 0.f};

  #pragma unroll 1
  for (int k0 = 0; k0 < K; k0 += 64) {
    __syncthreads();
    gload16(ap[0] + k0, la[0]); gload16(ap[1] + k0, la[1]);
    gload16(ap[2] + k0, la[2]); gload16(ap[3] + k0, la[3]);
    gload16(bp[0] + k0, lb[0]); gload16(bp[1] + k0, lb[1]);
    gload16(bp[2] + k0, lb[2]); gload16(bp[3] + k0, lb[3]);
    __syncthreads();
    #pragma unroll
    for (int ks = 0; ks < 2; ks++) {
      bfrag8 wfr[4], xfr[4];
      #pragma unroll
      for (int nt = 0; nt < 4; nt++)
        wfr[nt] = *(const bfrag8*)((const char*)Bs + (b_off[nt] ^ (ks * 64)));
      #pragma unroll
      for (int mt = 0; mt < 4; mt++)
        xfr[mt] = *(const bfrag8*)((const char*)As + (a_off[mt] ^ (ks * 64)));
      #pragma unroll
      for (int mt = 0; mt < 4; mt++)
        #pragma unroll
        for (int nt = 0; nt < 4; nt++)   // weights as Arg0: their index -> quad*4+reg
          acc[mt][nt] = __builtin_amdgcn_mfma_f32_16x16x32_bf16(wfr[nt], xfr[mt], acc[mt][nt], 0, 0, 0);
    }
  }

  // thread (quad,ln): rows m = m0+wr*64+mt*16+ln ; cols n0+wc*64+nt*16+quad*4+{0..3}
  #pragma unroll
  for (int nt = 0; nt < 4; nt++) {
    int ncol = n0 + wc * 64 + nt * 16 + quad * 4;
    float4 bv = *(const float4*)&bias[ncol];
    #pragma unroll
    for (int mt = 0; mt < 4; mt++) {
      int row = m0 + wr * 64 + mt * 16 + ln;
      if (row < Mdim) {
        float v0 = acc[mt][nt][0] + bv.x, v1 = acc[mt][nt][1] + bv.y;
        float v2 = acc[mt][nt][2] + bv.z, v3 = acc[mt][nt][3] + bv.w;
        if (RELU) {
          v0 = fmaxf(v0, 0.f); v1 = fmaxf(v1, 0.f);
          v2 = fmaxf(v2, 0.f); v3 = fmaxf(v3, 0.f);
        }
        bf16 o[4] = {(bf16)v0, (bf16)v1, (bf16)v2, (bf16)v3};
        *(uint2*)&C[(size_t)row * N + ncol] = *(uint2*)o;
      }
    }
  }
}

// ---------------- MSDA sampling v2: one wave per (m,h), lane = (point,corner) ----
// v1 (cg-split) duplicated the per-corner address/valid/weight chain 4x per lane
// and was VALU-issue bound (VALUBusy ~104%). v2: each lane owns ONE corner of one
// point and gathers all 32 head-cols (64B contiguous), so the corner chain is paid
// once. Cross-lane sum (64 lanes x 32 f32) goes through padded LDS
// ([64 rows][9 f32x2], stride 72B -> b64 reads at the 4-way wave64 floor) in two
// phases of 8 col-pairs (4.5KB/wave, 18KB/block), finishing with a 3-step
// shuffle-xor over the row-group bits. Reduction rides the DS pipe, which is idle.
__device__ __forceinline__ f32x2 bfpair(uint u, f32x2 s) {
  f32x2 r = {__uint_as_float(u << 16), __uint_as_float(u & 0xffff0000u)};
  return r * s;
}

__device__ __forceinline__ void msda_phase(
    uint4 A, uint4 B, f32x2 cw2, float* lrow, const float* rb,
    bf16* outp, int lane) {
  f32x2* lp = (f32x2*)lrow;
  lp[0] = bfpair(A.x, cw2); lp[1] = bfpair(A.y, cw2);
  lp[2] = bfpair(A.z, cw2); lp[3] = bfpair(A.w, cw2);
  lp[4] = bfpair(B.x, cw2); lp[5] = bfpair(B.y, cw2);
  lp[6] = bfpair(B.z, cw2); lp[7] = bfpair(B.w, cw2);
  // wave-internal producer->consumer through LDS: wait for this wave's writes.
  asm volatile("s_waitcnt lgkmcnt(0)" ::: "memory");
  f32x2 s0 = *(const f32x2*)(rb + 0 * 18) + *(const f32x2*)(rb + 1 * 18);
  f32x2 s1 = *(const f32x2*)(rb + 2 * 18) + *(const f32x2*)(rb + 3 * 18);
  f32x2 s2 = *(const f32x2*)(rb + 4 * 18) + *(const f32x2*)(rb + 5 * 18);
  f32x2 s3 = *(const f32x2*)(rb + 6 * 18) + *(const f32x2*)(rb + 7 * 18);
  f32x2 s = (s0 + s1) + (s2 + s3);
  #pragma unroll
  for (int msk = 8; msk < 64; msk <<= 1) {
    s.x += __shfl_xor(s.x, msk);
    s.y += __shfl_xor(s.y, msk);
  }
  if (lane < 8) {
    bf16 t2[2] = {(bf16)s.x, (bf16)s.y};
    *(uint*)(outp + lane * 2) = *(uint*)t2;
  }
  // block compiler from hoisting next phase's LDS writes above this phase's reads
  // (cross-lane hazard is invisible to per-lane alias analysis).
  asm volatile("" ::: "memory");
}

__global__ __launch_bounds__(256) void msda_sample(
    const bf16* __restrict__ VOA,     // [B*LIN, 640]
    const float* __restrict__ ref,    // [M, 4, 2]
    bf16* __restrict__ sampled) {     // [M, 256]
  __shared__ __align__(16) float red[4][64][18];   // [wave][row][9 f32x2 pad]
  int wave = threadIdx.x >> 6;
  int gw = (blockIdx.x * 256 + threadIdx.x) >> 6;
  int lane = threadIdx.x & 63;
  int m = gw >> 3, h = gw & 7;
  if (m >= M_) return;
  int b = m / LIN;
  int p = lane >> 2, corner = lane & 3;
  int l = p >> 2, pt = p & 3;
  int Wl = (l == 0) ? 100 : (l == 1) ? 50 : (l == 2) ? 25 : 13;
  int Hl = Wl;
  int st = (l == 0) ? 0 : (l == 1) ? 10000 : (l == 2) ? 12500 : 13125;

  const bf16* row = VOA + (size_t)m * 640;
  // softmax over the 16 points (no max-subtract: |logit| small, exp safe)
  float e = __expf((float)row[512 + h * 16 + p]);
  float se = e;
  #pragma unroll
  for (int msk = 4; msk < 64; msk <<= 1) se += __shfl_xor(se, msk);
  float w = e / se;

  f32x2 rxy = *(const f32x2*)&ref[((size_t)m * 4 + l) * 2];
  uint oxy = *(const uint*)&row[256 + ((h * 4 + l) * 4 + pt) * 2];
  float ox = __uint_as_float(oxy << 16);
  float oy = __uint_as_float(oxy & 0xffff0000u);
  float x = rxy.x * (float)Wl + ox - 0.5f;
  float y = rxy.y * (float)Hl + oy - 0.5f;
  float x0f = floorf(x), y0f = floorf(y);
  float dx = x - x0f, dy = y - y0f;
  int cx = corner & 1, cy = corner >> 1;
  int xi = (int)x0f + cx, yi = (int)y0f + cy;
  bool valid = (xi >= 0) & (xi < Wl) & (yi >= 0) & (yi < Hl);  // zero padding
  int xc = min(max(xi, 0), Wl - 1);
  int yc = min(max(yi, 0), Hl - 1);
  float cw = (cx ? dx : 1.f - dx) * (cy ? dy : 1.f - dy) * w;
  cw = valid ? cw : 0.f;

  // gather all 32 head-cols (64B) of this lane's corner
  const bf16* vp = VOA + ((size_t)(b * LIN + st) + (size_t)(yc * Wl + xc)) * 640 + h * 32;
  uint4 va = *(const uint4*)(vp);
  uint4 vb = *(const uint4*)(vp + 8);
  uint4 vc = *(const uint4*)(vp + 16);
  uint4 vd = *(const uint4*)(vp + 24);

  f32x2 cw2 = {cw, cw};
  float* lrow = &red[wave][lane][0];
  const float* rb = &red[wave][(lane >> 3) * 8][0] + (lane & 7) * 2;
  bf16* outp = sampled + (size_t)m * 256 + h * 32;

  msda_phase(va, vb, cw2, lrow, rb, outp, lane);        // col pairs 0..7
  msda_phase(vc, vd, cw2, lrow, rb, outp + 16, lane);   // col pairs 8..15
}

// ---------------- LayerNorm over 256: y = LN(a + res)*g + b ----------------
__device__ inline float4 load4f(const float* p) { return *(const float4*)p; }
__device__ inline float4 load4f(const bf16* p) {
  bf16x4 v = *(const bf16x4*)p;
  float4 r = {(float)v[0], (float)v[1], (float)v[2], (float)v[3]};
  return r;
}
template<typename RT>
__global__ __launch_bounds__(256) void ln_kernel(
    const bf16* __restrict__ a, const RT* __restrict__ res,
    const float* __restrict__ g, const float* __restrict__ beta,
    float* __restrict__ out_f, bf16* __restrict__ out_b, int Mdim) {
  int wave = threadIdx.x >> 6, lane = threadIdx.x & 63;
  int row = blockIdx.x * 4 + wave;
  if (row >= Mdim) return;
  size_t base = (size_t)row * 256 + lane * 4;
  float4 av = load4f(a + base);
  float4 rv = load4f(res + base);
  float4 v = {av.x + rv.x, av.y + rv.y, av.z + rv.z, av.w + rv.w};
  float s = v.x + v.y + v.z + v.w;
  #pragma unroll
  for (int msk = 1; msk < 64; msk <<= 1) s += __shfl_xor(s, msk);
  float mean = s * (1.f / 256.f);
  float4 d = {v.x - mean, v.y - mean, v.z - mean, v.w - mean};
  float sq = d.x * d.x + d.y * d.y + d.z * d.z + d.w * d.w;
  #pragma unroll
  for (int msk = 1; msk < 64; msk <<= 1) sq += __shfl_xor(sq, msk);
  float inv = rsqrtf(sq * (1.f / 256.f) + 1e-5f);
  float4 gv = *(const float4*)(g + lane * 4);
  float4 bv = *(const float4*)(beta + lane * 4);
  float4 y = {d.x * inv * gv.x + bv.x, d.y * inv * gv.y + bv.y,
              d.z * inv * gv.z + bv.z, d.w * inv * gv.w + bv.w};
  if (out_f) *(float4*)(out_f + base) = y;
  if (out_b) {
    bf16 t4[4] = {(bf16)y.x, (bf16)y.y, (bf16)y.z, (bf16)y.w};
    *(uint2*)(out_b + base) = *(uint2*)t4;
  }
}

extern "C" void kernel_launch(void* const* d_in, const int* in_sizes, int n_in,
                              void* d_out, int out_size, void* d_ws, size_t ws_size,
                              hipStream_t stream) {
  const float* src     = (const float*)d_in[0];
  const float* pos     = (const float*)d_in[1];
  const float* refpts  = (const float*)d_in[2];
  const float* value_w = (const float*)d_in[5];
  const float* value_b = (const float*)d_in[6];
  const float* offs_w  = (const float*)d_in[7];
  const float* offs_b  = (const float*)d_in[8];
  const float* attn_w  = (const float*)d_in[9];
  const float* attn_b  = (const float*)d_in[10];
  const float* out_w   = (const float*)d_in[11];
  const float* out_b   = (const float*)d_in[12];
  const float* ln1_g   = (const float*)d_in[13];
  const float* ln1_b   = (const float*)d_in[14];
  const float* ff1_w   = (const float*)d_in[15];
  const float* ff1_b   = (const float*)d_in[16];
  const float* ff2_w   = (const float*)d_in[17];
  const float* ff2_b   = (const float*)d_in[18];
  const float* ln2_g   = (const float*)d_in[19];
  const float* ln2_b   = (const float*)d_in[20];

  char* ws = (char*)d_ws;
  size_t off = 0;
  auto take = [&](size_t bytes) -> char* {
    char* pp = ws + off;
    off += (bytes + 255) & ~(size_t)255;
    return pp;
  };
  float* q      = (float*)take((size_t)M_ * 256 * 4);
  size_t szQB   = (size_t)M_ * 256 * 2;
  size_t szVOA  = (size_t)M_ * 640 * 2;
  char* R       = take(szQB + szVOA + szQB);     // qb | VOA | sampled
  bf16* qb      = (bf16*)R;
  bf16* VOA     = (bf16*)(R + szQB);
  bf16* sampled = (bf16*)(R + szQB + szVOA);
  bf16* hb      = (bf16*)R;                      // alias: M*1024*2 <= region size
  bf16* tmp     = (bf16*)take(szQB);             // src2, then ff2 out
  bf16* x       = (bf16*)take(szQB);             // LN1 out (bf16)
  bf16* vowt    = (bf16*)take(640 * 256 * 2);
  bf16* outwt   = (bf16*)take(65536 * 2);
  bf16* f1wt    = (bf16*)take(262144 * 2);
  bf16* f2wt    = (bf16*)take(262144 * 2);
  float* vobias = (float*)take(640 * 4);
  (void)ws_size; (void)in_sizes; (void)n_in; (void)out_size;

  int n4 = M_ * 256 / 4;
  make_q<<<dim3((n4 + 255) / 256), dim3(256), 0, stream>>>(src, pos, q, qb, n4);
  prep_weights<<<dim3(1024, 7), dim3(256), 0, stream>>>(
      value_w, offs_w, attn_w, out_w, ff1_w, ff2_w, value_b, offs_b, attn_b,
      vowt, outwt, f1wt, f2wt, vobias);

  dim3 blk(256);
  int mt = (M_ + 127) / 128;  // 416
  gemm128<256, false><<<dim3(mt, 5), blk, 0, stream>>>(qb, vowt, vobias, VOA, M_, 640);
  msda_sample<<<dim3(M_ * 2), blk, 0, stream>>>(VOA, refpts, sampled);
  gemm128<256, false><<<dim3(mt, 2), blk, 0, stream>>>(sampled, outwt, out_b, tmp, M_, 256);
  ln_kernel<float><<<dim3((M_ + 3) / 4), blk, 0, stream>>>(tmp, q, ln1_g, ln1_b, nullptr, x, M_);
  gemm128<256, true><<<dim3(mt, 8), blk, 0, stream>>>(x, f1wt, ff1_b, hb, M_, 1024);
  gemm128<1024, false><<<dim3(mt, 2), blk, 0, stream>>>(hb, f2wt, ff2_b, tmp, M_, 256);
  ln_kernel<bf16><<<dim3((M_ + 3) / 4), blk, 0, stream>>>(tmp, x, ln2_g, ln2_b, (float*)d_out, nullptr, M_);
}

// Round 2
// 596.007 us; speedup vs baseline: 1.0596x; 1.0596x over previous
//
#include <hip/hip_runtime.h>
#include <hip/hip_bf16.h>

// ---- problem constants (fixed by setup_inputs) ----
#define B_    4
#define LIN   13294
#define M_    (B_*LIN)     // 53176
#define D_    256
#define NH_   8
#define NL_   4
#define NP_   4
#define DFF_  1024

typedef __bf16 bf16;
typedef unsigned int uint;
typedef __attribute__((ext_vector_type(8))) __bf16 bfrag8;
typedef __attribute__((ext_vector_type(4))) __bf16 bf16x4;
typedef __attribute__((ext_vector_type(4))) float facc4;
typedef __attribute__((ext_vector_type(2))) float f32x2;

// ---------------- elementwise: q = src + pos (fp32 + bf16) ----------------
__global__ __launch_bounds__(256) void make_q(const float* __restrict__ src,
                                              const float* __restrict__ pos,
                                              float* __restrict__ q,
                                              bf16* __restrict__ qb, int n4) {
  int i = blockIdx.x * 256 + threadIdx.x;
  if (i >= n4) return;
  float4 s = ((const float4*)src)[i];
  float4 p = ((const float4*)pos)[i];
  float4 v = {s.x + p.x, s.y + p.y, s.z + p.z, s.w + p.w};
  ((float4*)q)[i] = v;
  bf16 t4[4] = {(bf16)v.x, (bf16)v.y, (bf16)v.z, (bf16)v.w};
  ((uint2*)qb)[i] = *(uint2*)t4;
}

// ---------------- weight prep: transpose + bf16 convert ----------------
// vowt packs value_w^T (rows 0..255), offs_w^T (256..511), attn_w^T (512..639).
__global__ __launch_bounds__(256) void prep_weights(
    const float* __restrict__ vw, const float* __restrict__ ow,
    const float* __restrict__ aw, const float* __restrict__ outw,
    const float* __restrict__ f1w, const float* __restrict__ f2w,
    const float* __restrict__ vb, const float* __restrict__ ob,
    const float* __restrict__ ab,
    bf16* __restrict__ vowt, bf16* __restrict__ outwt,
    bf16* __restrict__ f1wt, bf16* __restrict__ f2wt, float* __restrict__ vobias) {
  int seg = blockIdx.y;
  int idx = blockIdx.x * 256 + threadIdx.x;
  if (seg == 6) {
    if (idx < 256) vobias[idx] = vb[idx];
    else if (idx < 512) vobias[idx] = ob[idx - 256];
    else if (idx < 640) vobias[idx] = ab[idx - 512];
    return;
  }
  const float* W; bf16* Wt; int K, N;
  switch (seg) {
    case 0: W = vw;   Wt = vowt;              K = 256;  N = 256;  break;
    case 1: W = ow;   Wt = vowt + 256 * 256;  K = 256;  N = 256;  break;
    case 2: W = aw;   Wt = vowt + 512 * 256;  K = 256;  N = 128;  break;
    case 3: W = outw; Wt = outwt;             K = 256;  N = 256;  break;
    case 4: W = f1w;  Wt = f1wt;              K = 256;  N = 1024; break;
    default: W = f2w; Wt = f2wt;              K = 1024; N = 256;  break;
  }
  if (idx < K * N) {
    int n = idx / K, k = idx - n * K;
    Wt[idx] = (bf16)W[k * N + n];
  }
}

// ---------------- async 16B global -> LDS (offset 0 only: HW-verified form) ----
__device__ __forceinline__ void gload16(const bf16* g, bf16* l) {
  __builtin_amdgcn_global_load_lds(
      (const __attribute__((address_space(1))) uint*)g,
      (__attribute__((address_space(3))) uint*)l, 16, 0, 0);
}

// ---------------- 128x128 MFMA GEMM, BK=32 double-buffered pipeline ----------
// v3: shallow-K shapes (K=256) exposed the __syncthreads vmcnt(0) drain every
// iteration (~300-900cy stall vs ~250cy compute). Now: 2 LDS buffers of BK=32
// (4x8KB = same 32KB footprint -> occupancy preserved), raw s_barrier + counted
// s_waitcnt vmcnt(4) so the next tile's loads stay in flight across barriers
// (T3/T4 minimum form). LDS lines are 128B holding a row-PAIR (2 rows x 32
// cols); chunk-slot XOR swizzle (slot ^ line&7) keeps ds_read_b128
// conflict-free; the staging global address is pre-swizzled (both-sides rule).
// MFMA operand-swapped (weights = Arg0) as before.
template<int K, bool RELU>
__global__ __launch_bounds__(256) void gemm128(
    const bf16* __restrict__ A, const bf16* __restrict__ Bt,
    const float* __restrict__ bias, bf16* __restrict__ C,
    int Mdim, int N) {
  __shared__ __align__(16) bf16 As[2][4096];   // [buf][64 lines x 128B]
  __shared__ __align__(16) bf16 Bs[2][4096];
  const int t = threadIdx.x, wave = t >> 6, lane = t & 63;
  const int m0 = blockIdx.x * 128, n0 = blockIdx.y * 128;
  const int wr = wave >> 1, wc = wave & 1;
  const int ln = lane & 15, quad = lane >> 4;

  // staging: 8 segments of 1KB per matrix; wave w owns segments w*2, w*2+1.
  // segment s, lane l writes LDS line L = s*8 + (l>>3), slot p = l&7.
  // slot p of line L holds logical (row = 2L + (lc>>2), kchunk = lc&3), lc = p ^ (L&7).
  const bf16* ap[2]; const bf16* bp[2];
  int sdst[2];
  #pragma unroll
  for (int j = 0; j < 2; j++) {
    int s = wave * 2 + j;
    int L = s * 8 + (lane >> 3);
    int lc = (lane & 7) ^ (L & 7);
    int r = 2 * L + (lc >> 2);
    int kq = (lc & 3) * 8;
    ap[j] = A + (size_t)min(m0 + r, Mdim - 1) * K + kq;
    bp[j] = Bt + (size_t)(n0 + r) * K + kq;
    sdst[j] = s * 512;                    // element offset of segment base
  }
  // fragment byte offsets within one buffer: row ra, k-chunk quad
  int a_off[4], b_off[4];
  #pragma unroll
  for (int i = 0; i < 4; i++) {
    int ra = wr * 64 + i * 16 + ln;
    int rb = wc * 64 + i * 16 + ln;
    a_off[i] = (ra >> 1) * 128 + (((((ra & 1) << 2) | quad) ^ ((ra >> 1) & 7)) * 16);
    b_off[i] = (rb >> 1) * 128 + (((((rb & 1) << 2) | quad) ^ ((rb >> 1) & 7)) * 16);
  }

  facc4 acc[4][4];
  #pragma unroll
  for (int mt = 0; mt < 4; mt++)
    #pragma unroll
    for (int nt = 0; nt < 4; nt++) acc[mt][nt] = (facc4){0.f, 0.f, 0.f, 0.f};

  constexpr int NT = K / 32;
  // prologue: stage t=0 -> buf0, t=1 -> buf1 (8 loads in flight)
  gload16(ap[0] + 0,  As[0] + sdst[0]);
  gload16(ap[1] + 0,  As[0] + sdst[1]);
  gload16(bp[0] + 0,  Bs[0] + sdst[0]);
  gload16(bp[1] + 0,  Bs[0] + sdst[1]);
  gload16(ap[0] + 32, As[1] + sdst[0]);
  gload16(ap[1] + 32, As[1] + sdst[1]);
  gload16(bp[0] + 32, Bs[1] + sdst[0]);
  gload16(bp[1] + 32, Bs[1] + sdst[1]);
  asm volatile("s_waitcnt vmcnt(4)" ::: "memory");   // buf0 (own 4) landed
  __builtin_amdgcn_s_barrier();                      // all waves: buf0 ready
  asm volatile("" ::: "memory");

  #pragma unroll 1
  for (int tt = 0; tt < NT; ++tt) {
    const char* ab = (const char*)As[tt & 1];
    const char* bb = (const char*)Bs[tt & 1];
    bfrag8 wfr[4], xfr[4];
    #pragma unroll
    for (int nt = 0; nt < 4; nt++)
      wfr[nt] = *(const bfrag8*)(bb + b_off[nt]);
    #pragma unroll
    for (int mt = 0; mt < 4; mt++)
      xfr[mt] = *(const bfrag8*)(ab + a_off[mt]);
    #pragma unroll
    for (int mt = 0; mt < 4; mt++)
      #pragma unroll
      for (int nt = 0; nt < 4; nt++)   // weights as Arg0: their index -> quad*4+reg
        acc[mt][nt] = __builtin_amdgcn_mfma_f32_16x16x32_bf16(wfr[nt], xfr[mt], acc[mt][nt], 0, 0, 0);

    if (tt + 2 < NT) {
      asm volatile("" ::: "memory");
      __builtin_amdgcn_s_barrier();              // all waves done reading buf[tt&1]
      int kk = (tt + 2) * 32;
      bf16* la = As[tt & 1]; bf16* lb = Bs[tt & 1];
      gload16(ap[0] + kk, la + sdst[0]);
      gload16(ap[1] + kk, la + sdst[1]);
      gload16(bp[0] + kk, lb + sdst[0]);
      gload16(bp[1] + kk, lb + sdst[1]);
      asm volatile("s_waitcnt vmcnt(4)" ::: "memory");   // (tt+1)'s loads landed
      __builtin_amdgcn_s_barrier();              // all waves: next buf ready
      asm volatile("" ::: "memory");
    } else if (tt + 1 < NT) {
      asm volatile("s_waitcnt vmcnt(0)" ::: "memory");
      __builtin_amdgcn_s_barrier();
      asm volatile("" ::: "memory");
    }
  }

  // thread (quad,ln): rows m = m0+wr*64+mt*16+ln ; cols n0+wc*64+nt*16+quad*4+{0..3}
  #pragma unroll
  for (int nt = 0; nt < 4; nt++) {
    int ncol = n0 + wc * 64 + nt * 16 + quad * 4;
    float4 bv = *(const float4*)&bias[ncol];
    #pragma unroll
    for (int mt = 0; mt < 4; mt++) {
      int row = m0 + wr * 64 + mt * 16 + ln;
      if (row < Mdim) {
        float v0 = acc[mt][nt][0] + bv.x, v1 = acc[mt][nt][1] + bv.y;
        float v2 = acc[mt][nt][2] + bv.z, v3 = acc[mt][nt][3] + bv.w;
        if (RELU) {
          v0 = fmaxf(v0, 0.f); v1 = fmaxf(v1, 0.f);
          v2 = fmaxf(v2, 0.f); v3 = fmaxf(v3, 0.f);
        }
        bf16 o[4] = {(bf16)v0, (bf16)v1, (bf16)v2, (bf16)v3};
        *(uint2*)&C[(size_t)row * N + ncol] = *(uint2*)o;
      }
    }
  }
}

// ---------------- MSDA sampling: one wave per (query m, head h) ----------------
// v1 layout (lane = point*4 + colgroup): VALU-bound but the best measured (162us).
// v2's corner-per-lane + LDS reduce moved the cost to the DS pipe and regressed.
__global__ __launch_bounds__(256) void msda_sample(
    const bf16* __restrict__ VOA,     // [B*LIN, 640]
    const float* __restrict__ ref,    // [M, 4, 2]
    bf16* __restrict__ sampled) {     // [M, 256]
  int gw = (blockIdx.x * 256 + threadIdx.x) >> 6;
  int lane = threadIdx.x & 63;
  int m = gw >> 3, h = gw & 7;
  if (m >= M_) return;
  int b = m / LIN;
  int p = lane >> 2, cg = lane & 3;
  int l = p >> 2, pt = p & 3;
  int Wl = (l == 0) ? 100 : (l == 1) ? 50 : (l == 2) ? 25 : 13;
  int Hl = Wl;
  int st = (l == 0) ? 0 : (l == 1) ? 10000 : (l == 2) ? 12500 : 13125;

  const bf16* row = VOA + (size_t)m * 640;
  // softmax over the 16 points (no max-subtract: |logit| small, exp safe)
  float e = __expf((float)row[512 + h * 16 + p]);
  float se = e;
  #pragma unroll
  for (int msk = 4; msk < 64; msk <<= 1) se += __shfl_xor(se, msk);
  float w = e / se;

  float rx = ref[((size_t)m * 4 + l) * 2 + 0];
  float ry = ref[((size_t)m * 4 + l) * 2 + 1];
  uint oxy = *(const uint*)&row[256 + ((h * 4 + l) * 4 + pt) * 2];
  float ox = __uint_as_float(oxy << 16);
  float oy = __uint_as_float(oxy & 0xffff0000u);
  float x = rx * (float)Wl + ox - 0.5f;
  float y = ry * (float)Hl + oy - 0.5f;
  float x0f = floorf(x), y0f = floorf(y);
  float dx = x - x0f, dy = y - y0f;
  int x0 = (int)x0f, y0 = (int)y0f;
  float wx1 = 1.f - dx, wy1 = 1.f - dy;

  f32x2 acc2[4];
  #pragma unroll
  for (int i = 0; i < 4; i++) acc2[i] = (f32x2){0.f, 0.f};

  size_t vbase = ((size_t)(b * LIN + st)) * 640 + h * 32 + cg * 8;
  #pragma unroll
  for (int c = 0; c < 4; c++) {
    int cx = c & 1, cy = c >> 1;
    int xi = x0 + cx, yi = y0 + cy;
    bool valid = (xi >= 0) & (xi < Wl) & (yi >= 0) & (yi < Hl);
    int xc = min(max(xi, 0), Wl - 1);
    int yc = min(max(yi, 0), Hl - 1);
    float cw = (cx ? dx : wx1) * (cy ? dy : wy1) * w;
    cw = valid ? cw : 0.f;
    uint off = (uint)(yc * Wl + xc) * 640u;
    const uint4 vv = *(const uint4*)(VOA + vbase + off);
    f32x2 cw2 = {cw, cw};
    f32x2 v0 = {__uint_as_float(vv.x << 16), __uint_as_float(vv.x & 0xffff0000u)};
    f32x2 v1 = {__uint_as_float(vv.y << 16), __uint_as_float(vv.y & 0xffff0000u)};
    f32x2 v2 = {__uint_as_float(vv.z << 16), __uint_as_float(vv.z & 0xffff0000u)};
    f32x2 v3 = {__uint_as_float(vv.w << 16), __uint_as_float(vv.w & 0xffff0000u)};
    acc2[0] = cw2 * v0 + acc2[0];
    acc2[1] = cw2 * v1 + acc2[1];
    acc2[2] = cw2 * v2 + acc2[2];
    acc2[3] = cw2 * v3 + acc2[3];
  }

  // reduce-scatter over the 16 points (lane bits 2..5), payload 8->4->2->1->1
  int sel = (lane >> 2) & 1;
  f32x2 sA0 = sel ? acc2[0] : acc2[2];
  f32x2 sA1 = sel ? acc2[1] : acc2[3];
  f32x2 kA0 = sel ? acc2[2] : acc2[0];
  f32x2 kA1 = sel ? acc2[3] : acc2[1];
  f32x2 rA0, rA1;
  rA0.x = __shfl_xor(sA0.x, 4); rA0.y = __shfl_xor(sA0.y, 4);
  rA1.x = __shfl_xor(sA1.x, 4); rA1.y = __shfl_xor(sA1.y, 4);
  kA0 += rA0; kA1 += rA1;

  int sel2 = (lane >> 3) & 1;
  f32x2 sB = sel2 ? kA0 : kA1;
  f32x2 kB = sel2 ? kA1 : kA0;
  f32x2 rB;
  rB.x = __shfl_xor(sB.x, 8); rB.y = __shfl_xor(sB.y, 8);
  kB += rB;

  int sel3 = (lane >> 4) & 1;
  float sC = sel3 ? kB.x : kB.y;
  float kC = sel3 ? kB.y : kB.x;
  kC += __shfl_xor(sC, 16);

  float v = kC + __shfl_xor(kC, 32);

  if (lane < 32) {
    int c = cg * 8 + ((lane >> 2) & 1) * 4 + ((lane >> 3) & 1) * 2 + ((lane >> 4) & 1);
    sampled[(size_t)m * 256 + h * 32 + c] = (bf16)v;
  }
}

// ---------------- LayerNorm over 256: y = LN(a + res)*g + b ----------------
__device__ inline float4 load4f(const float* p) { return *(const float4*)p; }
__device__ inline float4 load4f(const bf16* p) {
  bf16x4 v = *(const bf16x4*)p;
  float4 r = {(float)v[0], (float)v[1], (float)v[2], (float)v[3]};
  return r;
}
template<typename RT>
__global__ __launch_bounds__(256) void ln_kernel(
    const bf16* __restrict__ a, const RT* __restrict__ res,
    const float* __restrict__ g, const float* __restrict__ beta,
    float* __restrict__ out_f, bf16* __restrict__ out_b, int Mdim) {
  int wave = threadIdx.x >> 6, lane = threadIdx.x & 63;
  int row = blockIdx.x * 4 + wave;
  if (row >= Mdim) return;
  size_t base = (size_t)row * 256 + lane * 4;
  float4 av = load4f(a + base);
  float4 rv = load4f(res + base);
  float4 v = {av.x + rv.x, av.y + rv.y, av.z + rv.z, av.w + rv.w};
  float s = v.x + v.y + v.z + v.w;
  #pragma unroll
  for (int msk = 1; msk < 64; msk <<= 1) s += __shfl_xor(s, msk);
  float mean = s * (1.f / 256.f);
  float4 d = {v.x - mean, v.y - mean, v.z - mean, v.w - mean};
  float sq = d.x * d.x + d.y * d.y + d.z * d.z + d.w * d.w;
  #pragma unroll
  for (int msk = 1; msk < 64; msk <<= 1) sq += __shfl_xor(sq, msk);
  float inv = rsqrtf(sq * (1.f / 256.f) + 1e-5f);
  float4 gv = *(const float4*)(g + lane * 4);
  float4 bv = *(const float4*)(beta + lane * 4);
  float4 y = {d.x * inv * gv.x + bv.x, d.y * inv * gv.y + bv.y,
              d.z * inv * gv.z + bv.z, d.w * inv * gv.w + bv.w};
  if (out_f) *(float4*)(out_f + base) = y;
  if (out_b) {
    bf16 t4[4] = {(bf16)y.x, (bf16)y.y, (bf16)y.z, (bf16)y.w};
    *(uint2*)(out_b + base) = *(uint2*)t4;
  }
}

extern "C" void kernel_launch(void* const* d_in, const int* in_sizes, int n_in,
                              void* d_out, int out_size, void* d_ws, size_t ws_size,
                              hipStream_t stream) {
  const float* src     = (const float*)d_in[0];
  const float* pos     = (const float*)d_in[1];
  const float* refpts  = (const float*)d_in[2];
  const float* value_w = (const float*)d_in[5];
  const float* value_b = (const float*)d_in[6];
  const float* offs_w  = (const float*)d_in[7];
  const float* offs_b  = (const float*)d_in[8];
  const float* attn_w  = (const float*)d_in[9];
  const float* attn_b  = (const float*)d_in[10];
  const float* out_w   = (const float*)d_in[11];
  const float* out_b   = (const float*)d_in[12];
  const float* ln1_g   = (const float*)d_in[13];
  const float* ln1_b   = (const float*)d_in[14];
  const float* ff1_w   = (const float*)d_in[15];
  const float* ff1_b   = (const float*)d_in[16];
  const float* ff2_w   = (const float*)d_in[17];
  const float* ff2_b   = (const float*)d_in[18];
  const float* ln2_g   = (const float*)d_in[19];
  const float* ln2_b   = (const float*)d_in[20];

  char* ws = (char*)d_ws;
  size_t off = 0;
  auto take = [&](size_t bytes) -> char* {
    char* pp = ws + off;
    off += (bytes + 255) & ~(size_t)255;
    return pp;
  };
  float* q      = (float*)take((size_t)M_ * 256 * 4);
  size_t szQB   = (size_t)M_ * 256 * 2;
  size_t szVOA  = (size_t)M_ * 640 * 2;
  char* R       = take(szQB + szVOA + szQB);     // qb | VOA | sampled
  bf16* qb      = (bf16*)R;
  bf16* VOA     = (bf16*)(R + szQB);
  bf16* sampled = (bf16*)(R + szQB + szVOA);
  bf16* hb      = (bf16*)R;                      // alias: M*1024*2 <= region size
  bf16* tmp     = (bf16*)take(szQB);             // src2, then ff2 out
  bf16* x       = (bf16*)take(szQB);             // LN1 out (bf16)
  bf16* vowt    = (bf16*)take(640 * 256 * 2);
  bf16* outwt   = (bf16*)take(65536 * 2);
  bf16* f1wt    = (bf16*)take(262144 * 2);
  bf16* f2wt    = (bf16*)take(262144 * 2);
  float* vobias = (float*)take(640 * 4);
  (void)ws_size; (void)in_sizes; (void)n_in; (void)out_size;

  int n4 = M_ * 256 / 4;
  make_q<<<dim3((n4 + 255) / 256), dim3(256), 0, stream>>>(src, pos, q, qb, n4);
  prep_weights<<<dim3(1024, 7), dim3(256), 0, stream>>>(
      value_w, offs_w, attn_w, out_w, ff1_w, ff2_w, value_b, offs_b, attn_b,
      vowt, outwt, f1wt, f2wt, vobias);

  dim3 blk(256);
  int mt = (M_ + 127) / 128;  // 416
  gemm128<256, false><<<dim3(mt, 5), blk, 0, stream>>>(qb, vowt, vobias, VOA, M_, 640);
  msda_sample<<<dim3(M_ * 2), blk, 0, stream>>>(VOA, refpts, sampled);
  gemm128<256, false><<<dim3(mt, 2), blk, 0, stream>>>(sampled, outwt, out_b, tmp, M_, 256);
  ln_kernel<float><<<dim3((M_ + 3) / 4), blk, 0, stream>>>(tmp, q, ln1_g, ln1_b, nullptr, x, M_);
  gemm128<256, true><<<dim3(mt, 8), blk, 0, stream>>>(x, f1wt, ff1_b, hb, M_, 1024);
  gemm128<1024, false><<<dim3(mt, 2), blk, 0, stream>>>(hb, f2wt, ff2_b, tmp, M_, 256);
  ln_kernel<bf16><<<dim3((M_ + 3) / 4), blk, 0, stream>>>(tmp, x, ln2_g, ln2_b, (float*)d_out, nullptr, M_);
}